// Round 3
// baseline (326.520 us; speedup 1.0000x reference)
//
#include <hip/hip_runtime.h>
#include <cmath>

#define ROWS 4096      // B*N
#define DIM 768        // D
#define QKV_COLS 2304  // 3*D
#define NHEAD 12
#define HEAD_DIM 64
#define SEQ 2048

static constexpr float EPS_F = 1e-8f;

typedef __bf16 bfrag __attribute__((ext_vector_type(8)));   // 8 bf16 = 4 VGPR (MFMA A/B frag)
typedef float  f32x4 __attribute__((ext_vector_type(4)));   // MFMA C/D frag

__device__ __forceinline__ float wave_sum64(float v) {
#pragma unroll
  for (int off = 1; off < 64; off <<= 1) v += __shfl_xor(v, off, 64);
  return v;
}

__device__ __forceinline__ unsigned short f2bf(float f) {
  unsigned u = __float_as_uint(f);
  u += 0x7fffu + ((u >> 16) & 1u);
  return (unsigned short)(u >> 16);
}

// fast tanh(x)/x for x>0:  t=(e-1)/(e+1), e=2^(x*2*log2e);  ->1 as x->0
__device__ __forceinline__ float tanh_over_x(float x) {
  const float e  = __builtin_amdgcn_exp2f(x * 2.8853900817779268f);
  const float th = (e - 1.0f) * __builtin_amdgcn_rcpf(e + 1.0f);
  return (x < 1e-4f) ? 1.0f : th * __builtin_amdgcn_rcpf(x);
}

__device__ __forceinline__ void gl_lds16(const void* g, void* l) {
  __builtin_amdgcn_global_load_lds((const __attribute__((address_space(1))) void*)g,
                                   (__attribute__((address_space(3))) void*)l, 16, 0, 0);
}

// ------------- fused: log0 -> bf16 tangent vectors  +  weight f32->bf16 casts -------------
__global__ __launch_bounds__(256) void log0_conv(const float* __restrict__ x,
                                                 const float* __restrict__ cptr,
                                                 unsigned short* __restrict__ vout,
                                                 const float* __restrict__ wa, int na,
                                                 const float* __restrict__ wb, int nb,
                                                 unsigned short* __restrict__ da,
                                                 unsigned short* __restrict__ db) {
  if (blockIdx.x >= ROWS / 4) {
    const int i = ((blockIdx.x - ROWS / 4) * 256 + threadIdx.x) * 4;
    const float* s;
    unsigned short* d;
    int j;
    if (i < na) { s = wa; d = da; j = i; }
    else { j = i - na; if (j >= nb) return; s = wb; d = db; }
    const float4 v = *(const float4*)(s + j);
    ushort4 o;
    o.x = f2bf(v.x); o.y = f2bf(v.y); o.z = f2bf(v.z); o.w = f2bf(v.w);
    *(ushort4*)(d + j) = o;
    return;
  }
  const int lane = threadIdx.x & 63;
  const int row  = (blockIdx.x << 2) + (threadIdx.x >> 6);
  const float* xr = x + (size_t)row * DIM;
  unsigned short* vr = vout + (size_t)row * DIM;
  float vals[12];
  float ss = 0.f;
#pragma unroll
  for (int i = 0; i < 12; ++i) {
    float t = xr[lane + (i << 6)];
    vals[i] = t;
    ss += t * t;
  }
  ss = wave_sum64(ss);
  const float sc  = sqrtf(cptr[0]);
  const float n   = fmaxf(sqrtf(ss), EPS_F);
  const float scn = sc * n;
  const float t   = fminf(scn, 1.0f - 1e-7f);
  const float ath = 0.34657359027997264f *
                    __builtin_amdgcn_logf((1.0f + t) * __builtin_amdgcn_rcpf(1.0f - t));
  const float f   = (scn < 1e-4f) ? 1.0f : ath * __builtin_amdgcn_rcpf(scn);
#pragma unroll
  for (int i = 0; i < 12; ++i) vr[lane + (i << 6)] = f2bf(vals[i] * f);
}

// ---------------- final exp0: out = tanh(sc*n) * v / (sc*n) ----------------
__global__ __launch_bounds__(256) void exp0_out_kernel(const float* __restrict__ vin,
                                                       const float* __restrict__ cptr,
                                                       float* __restrict__ outp) {
  const int lane = threadIdx.x & 63;
  const int row  = (blockIdx.x << 2) + (threadIdx.x >> 6);
  const float* vr = vin + (size_t)row * DIM;
  float* orow = outp + (size_t)row * DIM;
  float vals[12];
  float ss = 0.f;
#pragma unroll
  for (int i = 0; i < 12; ++i) {
    float t = vr[lane + (i << 6)];
    vals[i] = t;
    ss += t * t;
  }
  ss = wave_sum64(ss);
  const float sc = sqrtf(cptr[0]);
  const float n  = fmaxf(sqrtf(ss), EPS_F);
  const float f  = tanh_over_x(sc * n);
#pragma unroll
  for (int i = 0; i < 12; ++i) orow[lane + (i << 6)] = vals[i] * f;
}

// ---------------- MFMA GEMM NT, prefetch double-buffered (proj GEMM) ----------------
template<int BM, int BN>
__global__ __launch_bounds__(256) void gemm_nt_dbuf(const unsigned short* __restrict__ A,
                                                    const unsigned short* __restrict__ B,
                                                    float* __restrict__ C,
                                                    int M, int Ncols, int K,
                                                    const float* __restrict__ bias) {
  constexpr int FI = BM / 32;
  constexpr int FJ = BN / 32;
  constexpr int CH = BM / 64;
  __shared__ unsigned short As[2][BM * 32];
  __shared__ unsigned short Bs[2][BN * 32];
  const int tid = threadIdx.x;
  const int w = tid >> 6, lane = tid & 63;
  const int lq = lane & 15, quad = lane >> 4;
  const int wr = w >> 1, wc = w & 1;
  const int row0 = blockIdx.y * BM;
  const int col0 = blockIdx.x * BN;
  const int srow  = lane >> 2;
  const int skoff = (lane & 3) << 3;

  f32x4 acc[FI][FJ];
#pragma unroll
  for (int i = 0; i < FI; ++i)
#pragma unroll
    for (int j = 0; j < FJ; ++j) acc[i][j] = (f32x4){0.f, 0.f, 0.f, 0.f};

  auto pf = [&](int k0, int buf) {
#pragma unroll
    for (int c = 0; c < CH; ++c) {
      const int r = c * 64 + w * 16;
      gl_lds16(A + (size_t)(row0 + r + srow) * K + k0 + skoff, &As[buf][r * 32]);
      gl_lds16(B + (size_t)(col0 + r + srow) * K + k0 + skoff, &Bs[buf][r * 32]);
    }
  };

  pf(0, 0);
  const int NIT = K / 32;
  for (int it = 0; it < NIT; ++it) {
    const int buf = it & 1;
    __syncthreads();
    if (it + 1 < NIT) pf((it + 1) * 32, buf ^ 1);

    bfrag af[FI], bfg[FJ];
#pragma unroll
    for (int i = 0; i < FI; ++i)
      af[i] = *(const bfrag*)&As[buf][(wr * (BM / 2) + i * 16 + lq) * 32 + (quad << 3)];
#pragma unroll
    for (int j = 0; j < FJ; ++j)
      bfg[j] = *(const bfrag*)&Bs[buf][(wc * (BN / 2) + j * 16 + lq) * 32 + (quad << 3)];
#pragma unroll
    for (int i = 0; i < FI; ++i)
#pragma unroll
      for (int j = 0; j < FJ; ++j)
        acc[i][j] = __builtin_amdgcn_mfma_f32_16x16x32_bf16(af[i], bfg[j], acc[i][j], 0, 0, 0);
  }

#pragma unroll
  for (int i = 0; i < FI; ++i) {
    const int crow = row0 + wr * (BM / 2) + i * 16 + (quad << 2);
#pragma unroll
    for (int j = 0; j < FJ; ++j) {
      const int col = col0 + wc * (BN / 2) + j * 16 + lq;
      const float bj = bias ? bias[col] : 0.0f;
      float* cp = C + (size_t)crow * Ncols + col;
#pragma unroll
      for (int r = 0; r < 4; ++r)
        cp[(size_t)r * Ncols] = acc[i][j][r] + bj;
    }
  }
}

// ------------- fused QKV GEMM: 128x128 m97-style + exp0/norm/V-transpose epilogue -------
__global__ __launch_bounds__(256) void gemm_qkv_fused(const unsigned short* __restrict__ A,
                                                      const unsigned short* __restrict__ B,
                                                      const float* __restrict__ cptr,
                                                      unsigned short* __restrict__ qh,
                                                      unsigned short* __restrict__ kh,
                                                      unsigned short* __restrict__ vth,
                                                      float* __restrict__ qnA,
                                                      float* __restrict__ qnB,
                                                      float* __restrict__ knA,
                                                      float* __restrict__ knB) {
  __shared__ unsigned short As[2][128 * 32];
  __shared__ unsigned short Bs[2][128 * 32];
  const int tid = threadIdx.x;
  const int w = tid >> 6, lane = tid & 63;
  const int lq = lane & 15, quad = lane >> 4;
  const int wr = w >> 1, wc = w & 1;
  const int row0 = blockIdx.y << 7;
  const int col0 = blockIdx.x << 7;
  const int srow  = lane >> 2;
  const int skoff = (lane & 3) << 3;

  f32x4 acc[4][4];
#pragma unroll
  for (int i = 0; i < 4; ++i)
#pragma unroll
    for (int j = 0; j < 4; ++j) acc[i][j] = (f32x4){0.f, 0.f, 0.f, 0.f};

  auto pf = [&](int k0, int buf) {
#pragma unroll
    for (int c = 0; c < 2; ++c) {
      const int r = c * 64 + w * 16;
      gl_lds16(A + (size_t)(row0 + r + srow) * DIM + k0 + skoff, &As[buf][r * 32]);
      gl_lds16(B + (size_t)(col0 + r + srow) * DIM + k0 + skoff, &Bs[buf][r * 32]);
    }
  };

  pf(0, 0);
  for (int it = 0; it < DIM / 32; ++it) {
    const int buf = it & 1;
    __syncthreads();
    if (it + 1 < DIM / 32) pf((it + 1) * 32, buf ^ 1);

    bfrag af[4], bfg[4];
#pragma unroll
    for (int i = 0; i < 4; ++i)
      af[i] = *(const bfrag*)&As[buf][((wr << 6) + (i << 4) + lq) * 32 + (quad << 3)];
#pragma unroll
    for (int j = 0; j < 4; ++j)
      bfg[j] = *(const bfrag*)&Bs[buf][((wc << 6) + (j << 4) + lq) * 32 + (quad << 3)];
#pragma unroll
    for (int i = 0; i < 4; ++i)
#pragma unroll
      for (int j = 0; j < 4; ++j)
        acc[i][j] = __builtin_amdgcn_mfma_f32_16x16x32_bf16(af[i], bfg[j], acc[i][j], 0, 0, 0);
  }

  // ---- fused epilogue ----
  const int colw = col0 + (wc << 6);          // wave's 64-col base = one head slice
  const int seg  = colw / DIM;                // 0=q, 1=k, 2=v
  const int hh   = (colw % DIM) >> 6;
  const int rowb = row0 + (wr << 6);

  if (seg == 2) {
#pragma unroll
    for (int i = 0; i < 4; ++i)
#pragma unroll
      for (int r = 0; r < 4; ++r) {
        const int rowg = rowb + (i << 4) + (quad << 2) + r;
        const int bh = (rowg >> 11) * NHEAD + hh;
        const int n_ = rowg & 2047;
#pragma unroll
        for (int j = 0; j < 4; ++j)
          vth[((size_t)bh * HEAD_DIM + (j << 4) + lq) * SEQ + n_] = f2bf(acc[i][j][r]);
      }
  } else {
    unsigned short* dst = seg ? kh : qh;
    float* nA = seg ? knA : qnA;
    float* nB = seg ? knB : qnB;
    const float sc = sqrtf(cptr[0]);
#pragma unroll
    for (int i = 0; i < 4; ++i)
#pragma unroll
      for (int r = 0; r < 4; ++r) {
        float ss = acc[i][0][r] * acc[i][0][r];
        ss = fmaf(acc[i][1][r], acc[i][1][r], ss);
        ss = fmaf(acc[i][2][r], acc[i][2][r], ss);
        ss = fmaf(acc[i][3][r], acc[i][3][r], ss);
        ss += __shfl_xor(ss, 1, 64);
        ss += __shfl_xor(ss, 2, 64);
        ss += __shfl_xor(ss, 4, 64);
        ss += __shfl_xor(ss, 8, 64);
        const float nn = fmaxf(sqrtf(ss), EPS_F);
        const float f  = tanh_over_x(sc * nn);
        const int rowg = rowb + (i << 4) + (quad << 2) + r;
        const int bh = (rowg >> 11) * NHEAD + hh;
        const int n_ = rowg & 2047;
        unsigned short* rp = dst + ((size_t)bh * SEQ + n_) * HEAD_DIM;
#pragma unroll
        for (int j = 0; j < 4; ++j)
          rp[(j << 4) + lq] = f2bf(acc[i][j][r] * f);
        if (lq == 0) {
          const float nrm = ss * f * f;
          nA[(size_t)bh * SEQ + n_] = nrm;
          nB[(size_t)bh * SEQ + n_] = 1.0f / (1.0f - fminf(nrm, 0.99f));
        }
      }
  }
}

// ------------- MFMA flash attention: barrier-free main loop, direct-global fragments ----
// 8 waves = 4 q-strips x 2 key-halves, grid 768 = 3 blocks/CU = 24 waves/CU.
// K and V fragments are 16B-contiguous in global (kh row-major, vth pre-transposed), so
// each wave loads them straight into VGPRs: no LDS staging, no global_load_lds, and NO
// __syncthreads in the main loop -> no vmcnt(0) barrier drain. The x4 re-read across the
// 4 q-strip waves of a CU is absorbed by L1 (4KB tile) / L2. Waves free-run; 24 streams
// hide load latency. Ps stays as the intra-wave LDS repack (DS in-order, no barrier).
// LDS 28672: Ps 8K + combine cbuf 16K + lbuf 4K. One barrier total (split-K combine).
__global__ __launch_bounds__(512, 6) void flash_mfma(const unsigned short* __restrict__ qh,
                                                     const unsigned short* __restrict__ kh,
                                                     const unsigned short* __restrict__ vth,
                                                     const float* __restrict__ qnA,
                                                     const float* __restrict__ qnB,
                                                     const float* __restrict__ knA,
                                                     const float* __restrict__ knB,
                                                     unsigned short* __restrict__ attn_out) {
  const int flat = blockIdx.x;
  const int bhid = flat % 24;
  const int qt   = flat / 24;
  const int h = bhid % NHEAD, b = bhid / NHEAD;
  const int bh = b * NHEAD + h;
  const int tid = threadIdx.x;
  const int w = tid >> 6, lane = tid & 63;
  const int lq = lane & 15, quad = lane >> 4;
  const int wq = w & 3;        // q-strip
  const int wh = w >> 2;       // key half

  __shared__ __align__(16) unsigned short Ps[8][16 * 32];  // per-wave [q][key] swizzled, 8K
  __shared__ __align__(16) float cbuf[256 * 16];           // combine: oacc of upper half, 16K
  __shared__ __align__(16) float lbuf[256 * 4];            // combine: lacc of upper half, 4K

  const unsigned short* qbase = qh + ((size_t)bh * SEQ + (size_t)qt * 64) * HEAD_DIM;
  const unsigned short* kb_ = kh + (size_t)bh * SEQ * HEAD_DIM;    // [key][hd]
  const unsigned short* vb_ = vth + (size_t)bh * HEAD_DIM * SEQ;   // [dd][seq]
  const float* knAb = knA + (size_t)bh * SEQ;
  const float* knBb = knB + (size_t)bh * SEQ;

  // Q fragments (B operand in S^T)
  bfrag aq[2];
#pragma unroll
  for (int khf = 0; khf < 2; ++khf)
    aq[khf] = *(const bfrag*)(qbase + (size_t)((wq << 4) + lq) * HEAD_DIM + khf * 32 + quad * 8);

  const float qnS = qnA[(size_t)bh * SEQ + qt * 64 + (wq << 4) + lq];
  const float rqS = 2.0f * qnB[(size_t)bh * SEQ + qt * 64 + (wq << 4) + lq];

  bfrag ones;
#pragma unroll
  for (int j = 0; j < 8; ++j) ones[j] = (__bf16)1.0f;

  f32x4 oacc[4];
  f32x4 lacc = (f32x4){0.f, 0.f, 0.f, 0.f};
#pragma unroll
  for (int d = 0; d < 4; ++d) oacc[d] = (f32x4){0.f, 0.f, 0.f, 0.f};
  const int psx = ((lq >> 2) & 3) << 3;  // Ps swizzle (per q-row)

  // fixed per-lane pieces of the fragment addresses
  const unsigned short* kfl = kb_ + (size_t)lq * HEAD_DIM + quad * 8;  // + key*64 (+khf*32)
  const unsigned short* vfl = vb_ + (size_t)lq * SEQ + quad * 8;       // + dd16*SEQ + key0

  for (int kt = 0; kt < 32; ++kt) {
    const int key0 = (wh << 10) + (kt << 5);

    // kn norms (L2-hot), issued early, consumed after the S MFMAs
    f32x4 kna[2], knr[2];
#pragma unroll
    for (int st = 0; st < 2; ++st) {
      kna[st] = *(const f32x4*)(knAb + key0 + st * 16 + (quad << 2));
      knr[st] = *(const f32x4*)(knBb + key0 + st * 16 + (quad << 2));
    }

    // ---- S^T strip [32k x 16q] = K·Q^T, K fragments direct from global ----
    f32x4 s[2];
#pragma unroll
    for (int st = 0; st < 2; ++st) s[st] = (f32x4){0.f, 0.f, 0.f, 0.f};
#pragma unroll
    for (int khf = 0; khf < 2; ++khf)
#pragma unroll
      for (int st = 0; st < 2; ++st) {
        const bfrag ak = *(const bfrag*)(kfl + (size_t)(key0 + st * 16) * HEAD_DIM + khf * 32);
        s[st] = __builtin_amdgcn_mfma_f32_16x16x32_bf16(ak, aq[khf], s[st], 0, 0, 0);
      }

    // ---- w = (inner + sqrt(inner^2-1))^(-1/8); pack 4 keys via v_perm ----
#pragma unroll
    for (int st = 0; st < 2; ++st) {
      unsigned u[4];
#pragma unroll
      for (int i = 0; i < 4; ++i) {
        float tt = fmaf(-2.0f, s[st][i], qnS + kna[st][i]);
        tt = fmaxf(tt, 0.0f);
        const float inner = fmaf(tt, rqS * knr[st][i], 1.0f);
        const float root = __builtin_amdgcn_sqrtf(fmaf(inner, inner, -1.0f));
        const float wgt = __builtin_amdgcn_exp2f(-0.125f * __builtin_amdgcn_logf(inner + root));
        u[i] = __float_as_uint(wgt);
      }
      uint2 pk;
      pk.x = __builtin_amdgcn_perm(u[1], u[0], 0x07060302u);
      pk.y = __builtin_amdgcn_perm(u[3], u[2], 0x07060302u);
      *(uint2*)&Ps[w][(lq << 5) + (((st << 4) + (quad << 2)) ^ psx)] = pk;
    }

    // ---- O += P·V ; l += P·1 (intra-wave Ps; V fragments direct from global) ----
    const bfrag ap = *(const bfrag*)&Ps[w][(lq << 5) + ((quad << 3) ^ psx)];
    lacc = __builtin_amdgcn_mfma_f32_16x16x32_bf16(ap, ones, lacc, 0, 0, 0);
#pragma unroll
    for (int d = 0; d < 4; ++d) {
      const bfrag bv = *(const bfrag*)(vfl + (size_t)(d << 4) * SEQ + key0);
      oacc[d] = __builtin_amdgcn_mfma_f32_16x16x32_bf16(ap, bv, oacc[d], 0, 0, 0);
    }
  }

  // ---- combine halves through LDS (single barrier) ----
  const int ci = (wq << 6) + lane;
  if (wh) {
    float* p = cbuf + ci * 16;
#pragma unroll
    for (int d = 0; d < 4; ++d) *(f32x4*)(p + (d << 2)) = oacc[d];
    *(f32x4*)(lbuf + (ci << 2)) = lacc;
  }
  __syncthreads();
  if (wh) return;

  {
    const float* p = cbuf + ci * 16;
#pragma unroll
    for (int d = 0; d < 4; ++d) oacc[d] += *(const f32x4*)(p + (d << 2));
    lacc += *(const f32x4*)(lbuf + (ci << 2));
  }

  float rl4[4];
#pragma unroll
  for (int i = 0; i < 4; ++i) rl4[i] = __builtin_amdgcn_rcpf(lacc[i]);

  unsigned short* ob = attn_out + ((size_t)b * SEQ + (size_t)qt * 64 + (wq << 4)) * DIM + h * HEAD_DIM;
#pragma unroll
  for (int d = 0; d < 4; ++d)
#pragma unroll
    for (int i = 0; i < 4; ++i)
      ob[(size_t)(quad * 4 + i) * DIM + d * 16 + lq] = f2bf(oacc[d][i] * rl4[i]);
}

extern "C" void kernel_launch(void* const* d_in, const int* in_sizes, int n_in,
                              void* d_out, int out_size, void* d_ws, size_t ws_size,
                              hipStream_t stream) {
  const float* x      = (const float*)d_in[0];
  const float* w_qkv  = (const float*)d_in[1];
  const float* w_proj = (const float*)d_in[2];
  const float* b_proj = (const float*)d_in[3];
  const float* curv   = (const float*)d_in[4];
  float* outp = (float*)d_out;

  float* ws = (float*)d_ws;
  // region A (bf16 3,145,728): v_tan_bf during QKV GEMM; attn_bf during proj GEMM
  unsigned short* v_tan_bf = (unsigned short*)ws;
  unsigned short* attn_bf  = (unsigned short*)ws;
  float* v_out = ws + 1572864;                         // 3,145,728 f
  unsigned short* qh  = (unsigned short*)(v_out + 3145728);
  unsigned short* kh  = qh + 3145728;
  unsigned short* vth = kh + 3145728;
  unsigned short* wqkv_bf  = vth + 3145728;            // 1,769,472 bf16
  unsigned short* wproj_bf = wqkv_bf + 1769472;        // 589,824 bf16
  float* qnA = (float*)(wproj_bf + 589824);            // 49,152 f each
  float* qnB = qnA + 49152;
  float* knA = qnB + 49152;
  float* knB = knA + 49152;

  log0_conv<<<dim3(ROWS / 4 + 2304), dim3(256), 0, stream>>>(
      x, curv, v_tan_bf, w_qkv, 1769472, w_proj, 589824, wqkv_bf, wproj_bf);
  gemm_qkv_fused<<<dim3(QKV_COLS / 128, ROWS / 128), dim3(256), 0, stream>>>(
      v_tan_bf, wqkv_bf, curv, qh, kh, vth, qnA, qnB, knA, knB);
  flash_mfma<<<dim3(768), dim3(512), 0, stream>>>(qh, kh, vth, qnA, qnB, knA, knB, attn_bf);
  gemm_nt_dbuf<64, 64><<<dim3(DIM / 64, ROWS / 64), dim3(256), 0, stream>>>(
      attn_bf, wproj_bf, v_out, ROWS, DIM, DIM, b_proj);
  exp0_out_kernel<<<dim3(ROWS / 4), dim3(256), 0, stream>>>(v_out, curv, outp);
}

// Round 4
// 202.216 us; speedup vs baseline: 1.6147x; 1.6147x over previous
//
#include <hip/hip_runtime.h>
#include <cmath>

#define ROWS 4096      // B*N
#define DIM 768        // D
#define QKV_COLS 2304  // 3*D
#define NHEAD 12
#define HEAD_DIM 64
#define SEQ 2048

static constexpr float EPS_F = 1e-8f;

typedef __bf16 bfrag __attribute__((ext_vector_type(8)));   // 8 bf16 = 4 VGPR (MFMA A/B frag)
typedef float  f32x4 __attribute__((ext_vector_type(4)));   // MFMA C/D frag
typedef unsigned u32x4 __attribute__((ext_vector_type(4)));

__device__ __forceinline__ float wave_sum64(float v) {
#pragma unroll
  for (int off = 1; off < 64; off <<= 1) v += __shfl_xor(v, off, 64);
  return v;
}

__device__ __forceinline__ unsigned short f2bf(float f) {
  unsigned u = __float_as_uint(f);
  u += 0x7fffu + ((u >> 16) & 1u);
  return (unsigned short)(u >> 16);
}

// fast tanh(x)/x for x>0:  t=(e-1)/(e+1), e=2^(x*2*log2e);  ->1 as x->0
__device__ __forceinline__ float tanh_over_x(float x) {
  const float e  = __builtin_amdgcn_exp2f(x * 2.8853900817779268f);
  const float th = (e - 1.0f) * __builtin_amdgcn_rcpf(e + 1.0f);
  return (x < 1e-4f) ? 1.0f : th * __builtin_amdgcn_rcpf(x);
}

__device__ __forceinline__ void gl_lds16(const void* g, void* l) {
  __builtin_amdgcn_global_load_lds((const __attribute__((address_space(1))) void*)g,
                                   (__attribute__((address_space(3))) void*)l, 16, 0, 0);
}

// ------------- fused: log0 -> bf16 tangent vectors  +  weight f32->bf16 casts -------------
__global__ __launch_bounds__(256) void log0_conv(const float* __restrict__ x,
                                                 const float* __restrict__ cptr,
                                                 unsigned short* __restrict__ vout,
                                                 const float* __restrict__ wa, int na,
                                                 const float* __restrict__ wb, int nb,
                                                 unsigned short* __restrict__ da,
                                                 unsigned short* __restrict__ db) {
  if (blockIdx.x >= ROWS / 4) {
    const int i = ((blockIdx.x - ROWS / 4) * 256 + threadIdx.x) * 4;
    const float* s;
    unsigned short* d;
    int j;
    if (i < na) { s = wa; d = da; j = i; }
    else { j = i - na; if (j >= nb) return; s = wb; d = db; }
    const float4 v = *(const float4*)(s + j);
    ushort4 o;
    o.x = f2bf(v.x); o.y = f2bf(v.y); o.z = f2bf(v.z); o.w = f2bf(v.w);
    *(ushort4*)(d + j) = o;
    return;
  }
  const int lane = threadIdx.x & 63;
  const int row  = (blockIdx.x << 2) + (threadIdx.x >> 6);
  const float* xr = x + (size_t)row * DIM;
  unsigned short* vr = vout + (size_t)row * DIM;
  float vals[12];
  float ss = 0.f;
#pragma unroll
  for (int i = 0; i < 12; ++i) {
    float t = xr[lane + (i << 6)];
    vals[i] = t;
    ss += t * t;
  }
  ss = wave_sum64(ss);
  const float sc  = sqrtf(cptr[0]);
  const float n   = fmaxf(sqrtf(ss), EPS_F);
  const float scn = sc * n;
  const float t   = fminf(scn, 1.0f - 1e-7f);
  const float ath = 0.34657359027997264f *
                    __builtin_amdgcn_logf((1.0f + t) * __builtin_amdgcn_rcpf(1.0f - t));
  const float f   = (scn < 1e-4f) ? 1.0f : ath * __builtin_amdgcn_rcpf(scn);
#pragma unroll
  for (int i = 0; i < 12; ++i) vr[lane + (i << 6)] = f2bf(vals[i] * f);
}

// ---------------- final exp0: out = tanh(sc*n) * v / (sc*n) ----------------
__global__ __launch_bounds__(256) void exp0_out_kernel(const float* __restrict__ vin,
                                                       const float* __restrict__ cptr,
                                                       float* __restrict__ outp) {
  const int lane = threadIdx.x & 63;
  const int row  = (blockIdx.x << 2) + (threadIdx.x >> 6);
  const float* vr = vin + (size_t)row * DIM;
  float* orow = outp + (size_t)row * DIM;
  float vals[12];
  float ss = 0.f;
#pragma unroll
  for (int i = 0; i < 12; ++i) {
    float t = vr[lane + (i << 6)];
    vals[i] = t;
    ss += t * t;
  }
  ss = wave_sum64(ss);
  const float sc = sqrtf(cptr[0]);
  const float n  = fmaxf(sqrtf(ss), EPS_F);
  const float f  = tanh_over_x(sc * n);
#pragma unroll
  for (int i = 0; i < 12; ++i) orow[lane + (i << 6)] = vals[i] * f;
}

// ---------------- MFMA GEMM NT, prefetch double-buffered (proj GEMM) ----------------
template<int BM, int BN>
__global__ __launch_bounds__(256) void gemm_nt_dbuf(const unsigned short* __restrict__ A,
                                                    const unsigned short* __restrict__ B,
                                                    float* __restrict__ C,
                                                    int M, int Ncols, int K,
                                                    const float* __restrict__ bias) {
  constexpr int FI = BM / 32;
  constexpr int FJ = BN / 32;
  constexpr int CH = BM / 64;
  __shared__ unsigned short As[2][BM * 32];
  __shared__ unsigned short Bs[2][BN * 32];
  const int tid = threadIdx.x;
  const int w = tid >> 6, lane = tid & 63;
  const int lq = lane & 15, quad = lane >> 4;
  const int wr = w >> 1, wc = w & 1;
  const int row0 = blockIdx.y * BM;
  const int col0 = blockIdx.x * BN;
  const int srow  = lane >> 2;
  const int skoff = (lane & 3) << 3;

  f32x4 acc[FI][FJ];
#pragma unroll
  for (int i = 0; i < FI; ++i)
#pragma unroll
    for (int j = 0; j < FJ; ++j) acc[i][j] = (f32x4){0.f, 0.f, 0.f, 0.f};

  auto pf = [&](int k0, int buf) {
#pragma unroll
    for (int c = 0; c < CH; ++c) {
      const int r = c * 64 + w * 16;
      gl_lds16(A + (size_t)(row0 + r + srow) * K + k0 + skoff, &As[buf][r * 32]);
      gl_lds16(B + (size_t)(col0 + r + srow) * K + k0 + skoff, &Bs[buf][r * 32]);
    }
  };

  pf(0, 0);
  const int NIT = K / 32;
  for (int it = 0; it < NIT; ++it) {
    const int buf = it & 1;
    __syncthreads();
    if (it + 1 < NIT) pf((it + 1) * 32, buf ^ 1);

    bfrag af[FI], bfg[FJ];
#pragma unroll
    for (int i = 0; i < FI; ++i)
      af[i] = *(const bfrag*)&As[buf][(wr * (BM / 2) + i * 16 + lq) * 32 + (quad << 3)];
#pragma unroll
    for (int j = 0; j < FJ; ++j)
      bfg[j] = *(const bfrag*)&Bs[buf][(wc * (BN / 2) + j * 16 + lq) * 32 + (quad << 3)];
#pragma unroll
    for (int i = 0; i < FI; ++i)
#pragma unroll
      for (int j = 0; j < FJ; ++j)
        acc[i][j] = __builtin_amdgcn_mfma_f32_16x16x32_bf16(af[i], bfg[j], acc[i][j], 0, 0, 0);
  }

#pragma unroll
  for (int i = 0; i < FI; ++i) {
    const int crow = row0 + wr * (BM / 2) + i * 16 + (quad << 2);
#pragma unroll
    for (int j = 0; j < FJ; ++j) {
      const int col = col0 + wc * (BN / 2) + j * 16 + lq;
      const float bj = bias ? bias[col] : 0.0f;
      float* cp = C + (size_t)crow * Ncols + col;
#pragma unroll
      for (int r = 0; r < 4; ++r)
        cp[(size_t)r * Ncols] = acc[i][j][r] + bj;
    }
  }
}

// ------------- fused QKV GEMM: 128x128 m97-style + exp0/norm/V-transpose epilogue -------
__global__ __launch_bounds__(256) void gemm_qkv_fused(const unsigned short* __restrict__ A,
                                                      const unsigned short* __restrict__ B,
                                                      const float* __restrict__ cptr,
                                                      unsigned short* __restrict__ qh,
                                                      unsigned short* __restrict__ kh,
                                                      unsigned short* __restrict__ vth,
                                                      float* __restrict__ qnA,
                                                      float* __restrict__ qnB,
                                                      float* __restrict__ knA,
                                                      float* __restrict__ knB) {
  __shared__ unsigned short As[2][128 * 32];
  __shared__ unsigned short Bs[2][128 * 32];
  const int tid = threadIdx.x;
  const int w = tid >> 6, lane = tid & 63;
  const int lq = lane & 15, quad = lane >> 4;
  const int wr = w >> 1, wc = w & 1;
  const int row0 = blockIdx.y << 7;
  const int col0 = blockIdx.x << 7;
  const int srow  = lane >> 2;
  const int skoff = (lane & 3) << 3;

  f32x4 acc[4][4];
#pragma unroll
  for (int i = 0; i < 4; ++i)
#pragma unroll
    for (int j = 0; j < 4; ++j) acc[i][j] = (f32x4){0.f, 0.f, 0.f, 0.f};

  auto pf = [&](int k0, int buf) {
#pragma unroll
    for (int c = 0; c < 2; ++c) {
      const int r = c * 64 + w * 16;
      gl_lds16(A + (size_t)(row0 + r + srow) * DIM + k0 + skoff, &As[buf][r * 32]);
      gl_lds16(B + (size_t)(col0 + r + srow) * DIM + k0 + skoff, &Bs[buf][r * 32]);
    }
  };

  pf(0, 0);
  for (int it = 0; it < DIM / 32; ++it) {
    const int buf = it & 1;
    __syncthreads();
    if (it + 1 < DIM / 32) pf((it + 1) * 32, buf ^ 1);

    bfrag af[4], bfg[4];
#pragma unroll
    for (int i = 0; i < 4; ++i)
      af[i] = *(const bfrag*)&As[buf][((wr << 6) + (i << 4) + lq) * 32 + (quad << 3)];
#pragma unroll
    for (int j = 0; j < 4; ++j)
      bfg[j] = *(const bfrag*)&Bs[buf][((wc << 6) + (j << 4) + lq) * 32 + (quad << 3)];
#pragma unroll
    for (int i = 0; i < 4; ++i)
#pragma unroll
      for (int j = 0; j < 4; ++j)
        acc[i][j] = __builtin_amdgcn_mfma_f32_16x16x32_bf16(af[i], bfg[j], acc[i][j], 0, 0, 0);
  }

  // ---- fused epilogue ----
  const int colw = col0 + (wc << 6);          // wave's 64-col base = one head slice
  const int seg  = colw / DIM;                // 0=q, 1=k, 2=v
  const int hh   = (colw % DIM) >> 6;
  const int rowb = row0 + (wr << 6);

  if (seg == 2) {
#pragma unroll
    for (int i = 0; i < 4; ++i)
#pragma unroll
      for (int r = 0; r < 4; ++r) {
        const int rowg = rowb + (i << 4) + (quad << 2) + r;
        const int bh = (rowg >> 11) * NHEAD + hh;
        const int n_ = rowg & 2047;
#pragma unroll
        for (int j = 0; j < 4; ++j)
          vth[((size_t)bh * HEAD_DIM + (j << 4) + lq) * SEQ + n_] = f2bf(acc[i][j][r]);
      }
  } else {
    unsigned short* dst = seg ? kh : qh;
    float* nA = seg ? knA : qnA;
    float* nB = seg ? knB : qnB;
    const float sc = sqrtf(cptr[0]);
#pragma unroll
    for (int i = 0; i < 4; ++i)
#pragma unroll
      for (int r = 0; r < 4; ++r) {
        float ss = acc[i][0][r] * acc[i][0][r];
        ss = fmaf(acc[i][1][r], acc[i][1][r], ss);
        ss = fmaf(acc[i][2][r], acc[i][2][r], ss);
        ss = fmaf(acc[i][3][r], acc[i][3][r], ss);
        ss += __shfl_xor(ss, 1, 64);
        ss += __shfl_xor(ss, 2, 64);
        ss += __shfl_xor(ss, 4, 64);
        ss += __shfl_xor(ss, 8, 64);
        const float nn = fmaxf(sqrtf(ss), EPS_F);
        const float f  = tanh_over_x(sc * nn);
        const int rowg = rowb + (i << 4) + (quad << 2) + r;
        const int bh = (rowg >> 11) * NHEAD + hh;
        const int n_ = rowg & 2047;
        unsigned short* rp = dst + ((size_t)bh * SEQ + n_) * HEAD_DIM;
#pragma unroll
        for (int j = 0; j < 4; ++j)
          rp[(j << 4) + lq] = f2bf(acc[i][j][r] * f);
        if (lq == 0) {
          const float nrm = ss * f * f;
          nA[(size_t)bh * SEQ + n_] = nrm;
          nB[(size_t)bh * SEQ + n_] = 1.0f / (1.0f - fminf(nrm, 0.99f));
        }
      }
  }
}

// ------------- MFMA flash attention: triple-buffered LDS, counted-vmcnt pipeline -------
// 8 waves = 4 q-strips x 2 key-halves, grid 768 = 3 blocks/CU = 24 waves/CU.
// K/V staged via global_load_lds into 3 LDS buffers, prefetch issued 2 tiles ahead; raw
// s_barrier preceded only by vmcnt(2) (steady-state no-op: the compiler's wait for the
// kn loads each iteration FIFO-drains the older tile loads) -> no vmcnt(0) drain in the
// loop. P^T->P redistribution done IN-REGISTER via 8 ds_bpermute + selects (no Ps LDS):
// target reg r' of lane(lq,quad) = u32 idx quad*4+r' -> src lane ((2*quad+(r'>>1))&3)*16+lq,
// src reg (quad>>1)*2+(r'&1). LDS 49152 = 3 bufs x 2 halves x (4K K + 4K V).
__global__ __launch_bounds__(512, 6) void flash_mfma(const unsigned short* __restrict__ qh,
                                                     const unsigned short* __restrict__ kh,
                                                     const unsigned short* __restrict__ vth,
                                                     const float* __restrict__ qnA,
                                                     const float* __restrict__ qnB,
                                                     const float* __restrict__ knA,
                                                     const float* __restrict__ knB,
                                                     unsigned short* __restrict__ attn_out) {
  const int flat = blockIdx.x;
  const int bhid = flat % 24;
  const int qt   = flat / 24;
  const int h = bhid % NHEAD, b = bhid / NHEAD;
  const int bh = b * NHEAD + h;
  const int tid = threadIdx.x;
  const int w = tid >> 6, lane = tid & 63;
  const int lq = lane & 15, quad = lane >> 4;
  const int wq = w & 3;        // q-strip
  const int wh = w >> 2;       // key half

  __shared__ __align__(16) unsigned short Ks[3][2][32 * 64];  // [buf][half][key][hd] swizzled
  __shared__ __align__(16) unsigned short Vt[3][2][64 * 32];  // [buf][half] d-paired, swizzled

  const unsigned short* qbase = qh + ((size_t)bh * SEQ + (size_t)qt * 64) * HEAD_DIM;
  const float* knAb = knA + (size_t)bh * SEQ;
  const float* knBb = knB + (size_t)bh * SEQ;
  const char* khb = (const char*)(kh + (size_t)bh * SEQ * HEAD_DIM);
  const char* vtb = (const char*)(vth + (size_t)bh * HEAD_DIM * SEQ);

  // K staging: wave loads local rows wq*8..wq*8+7 of its half's 32-row tile
  const int krow = lane >> 3;                       // 0..7
  const int koff = ((wq << 3) + krow) * 128 + (((lane & 7) ^ krow) << 4);
  // V staging: chunk c of the 4KB d-paired tile
  const int c     = (wq << 6) + lane;               // 0..255
  const int vrow2 = c >> 3;
  const int vd    = (vrow2 << 1) + ((c >> 2) & 1);
  const int vg    = (c & 3) ^ (vrow2 & 3);
  const size_t voffb = (size_t)vd * (SEQ * 2);

  auto prefetch = [&](int kt, int buf) {
    const int kb = (wh << 10) + (kt << 5);
    gl_lds16(khb + (size_t)kb * 128 + koff, (char*)&Ks[buf][wh][0] + (wq << 10));
    gl_lds16(vtb + voffb + (size_t)(kb + (vg << 3)) * 2, (char*)&Vt[buf][wh][0] + (wq << 10));
  };

  // Q fragments (B operand in S^T)
  bfrag aq[2];
#pragma unroll
  for (int khf = 0; khf < 2; ++khf)
    aq[khf] = *(const bfrag*)(qbase + (size_t)((wq << 4) + lq) * HEAD_DIM + khf * 32 + quad * 8);

  const float qnS = qnA[(size_t)bh * SEQ + qt * 64 + (wq << 4) + lq];
  const float rqS = 2.0f * qnB[(size_t)bh * SEQ + qt * 64 + (wq << 4) + lq];

  bfrag ones;
#pragma unroll
  for (int j = 0; j < 8; ++j) ones[j] = (__bf16)1.0f;

  f32x4 oacc[4];
  f32x4 lacc = (f32x4){0.f, 0.f, 0.f, 0.f};
#pragma unroll
  for (int d = 0; d < 4; ++d) oacc[d] = (f32x4){0.f, 0.f, 0.f, 0.f};
  const int swz = lq & 7;             // Ks read swizzle (row&7)
  const int vsw = (lq >> 1) & 3;      // Vt read swizzle (row2&3)

  // bpermute source-lane byte addresses for the P redistribution
  const int adrA = ((((quad << 1) & 3) << 4) | lq) << 2;
  const int adrB = (((((quad << 1) + 1) & 3) << 4) | lq) << 2;
  const bool qlo = quad < 2;

  prefetch(0, 0);
  prefetch(1, 1);
  int bufc = 0;
  for (int kt = 0; kt < 32; ++kt) {
    const int key0 = (wh << 10) + (kt << 5);
    asm volatile("s_waitcnt vmcnt(2)" ::: "memory");  // own tile-kt loads landed
    __builtin_amdgcn_s_barrier();                     // all waves' tile-kt loads landed
    __builtin_amdgcn_sched_barrier(0);

    // kn norms (consumed in transform; compiler's wait FIFO-drains older tile loads)
    f32x4 kna[2], knr[2];
#pragma unroll
    for (int st = 0; st < 2; ++st) {
      kna[st] = *(const f32x4*)(knAb + key0 + st * 16 + (quad << 2));
      knr[st] = *(const f32x4*)(knBb + key0 + st * 16 + (quad << 2));
    }
    __builtin_amdgcn_sched_barrier(0);

    if (kt + 2 < 32) {
      const int bufn = bufc >= 1 ? bufc - 1 : bufc + 2;  // (bufc+2)%3
      prefetch(kt + 2, bufn);
    }

    // ---- S^T strip [32k x 16q] = K·Q^T via MFMA ----
    f32x4 s[2];
#pragma unroll
    for (int st = 0; st < 2; ++st) s[st] = (f32x4){0.f, 0.f, 0.f, 0.f};
#pragma unroll
    for (int khf = 0; khf < 2; ++khf)
#pragma unroll
      for (int st = 0; st < 2; ++st) {
        const bfrag ak = *(const bfrag*)&Ks[bufc][wh][(st * 16 + lq) * 64 + (((khf << 2) + quad) ^ swz) * 8];
        s[st] = __builtin_amdgcn_mfma_f32_16x16x32_bf16(ak, aq[khf], s[st], 0, 0, 0);
      }

    // ---- w = (inner + sqrt(inner^2-1))^(-1/8); pack pairs via v_perm ----
    unsigned pk[4];   // [st*2+h]: bf16 pair, u32-idx = st*8 + quad*2 + h
#pragma unroll
    for (int st = 0; st < 2; ++st) {
      unsigned u[4];
#pragma unroll
      for (int i = 0; i < 4; ++i) {
        float tt = fmaf(-2.0f, s[st][i], qnS + kna[st][i]);
        tt = fmaxf(tt, 0.0f);
        const float inner = fmaf(tt, rqS * knr[st][i], 1.0f);
        const float root = __builtin_amdgcn_sqrtf(fmaf(inner, inner, -1.0f));
        const float wgt = __builtin_amdgcn_exp2f(-0.125f * __builtin_amdgcn_logf(inner + root));
        u[i] = __float_as_uint(wgt);
      }
      pk[st * 2 + 0] = __builtin_amdgcn_perm(u[1], u[0], 0x07060302u);
      pk[st * 2 + 1] = __builtin_amdgcn_perm(u[3], u[2], 0x07060302u);
    }

    // ---- in-register P^T -> P redistribution (8 bpermute + 4 selects) ----
    u32x4 pr;
    {
      const unsigned a0 = (unsigned)__builtin_amdgcn_ds_bpermute(adrA, (int)pk[0]);
      const unsigned a1 = (unsigned)__builtin_amdgcn_ds_bpermute(adrA, (int)pk[2]);
      pr.x = qlo ? a0 : a1;
      const unsigned b0 = (unsigned)__builtin_amdgcn_ds_bpermute(adrA, (int)pk[1]);
      const unsigned b1 = (unsigned)__builtin_amdgcn_ds_bpermute(adrA, (int)pk[3]);
      pr.y = qlo ? b0 : b1;
      const unsigned c0 = (unsigned)__builtin_amdgcn_ds_bpermute(adrB, (int)pk[0]);
      const unsigned c1 = (unsigned)__builtin_amdgcn_ds_bpermute(adrB, (int)pk[2]);
      pr.z = qlo ? c0 : c1;
      const unsigned d0 = (unsigned)__builtin_amdgcn_ds_bpermute(adrB, (int)pk[1]);
      const unsigned d1 = (unsigned)__builtin_amdgcn_ds_bpermute(adrB, (int)pk[3]);
      pr.w = qlo ? d0 : d1;
    }
    const bfrag ap = __builtin_bit_cast(bfrag, pr);

    // ---- O += P·V ; l += P·1 ----
    lacc = __builtin_amdgcn_mfma_f32_16x16x32_bf16(ap, ones, lacc, 0, 0, 0);
#pragma unroll
    for (int d = 0; d < 4; ++d) {
      const int dd = (d << 4) + lq;
      const bfrag bv = *(const bfrag*)&Vt[bufc][wh][(dd >> 1) * 64 + (dd & 1) * 32 + (quad ^ vsw) * 8];
      oacc[d] = __builtin_amdgcn_mfma_f32_16x16x32_bf16(ap, bv, oacc[d], 0, 0, 0);
    }

    bufc = bufc == 2 ? 0 : bufc + 1;
  }

  // ---- combine halves through LDS (reuse tile space) ----
  __syncthreads();  // all waves done with tiles
  float* cbuf = (float*)&Ks[0][0][0];   // 16 KiB: oacc of upper half
  float* lbuf = (float*)&Vt[0][0][0];   // 4 KiB: lacc of upper half
  const int ci = (wq << 6) + lane;
  if (wh) {
    float* p = cbuf + ci * 16;
#pragma unroll
    for (int d = 0; d < 4; ++d) *(f32x4*)(p + (d << 2)) = oacc[d];
    *(f32x4*)(lbuf + (ci << 2)) = lacc;
  }
  __syncthreads();
  if (wh) return;

  {
    const float* p = cbuf + ci * 16;
#pragma unroll
    for (int d = 0; d < 4; ++d) oacc[d] += *(const f32x4*)(p + (d << 2));
    lacc += *(const f32x4*)(lbuf + (ci << 2));
  }

  float rl4[4];
#pragma unroll
  for (int i = 0; i < 4; ++i) rl4[i] = __builtin_amdgcn_rcpf(lacc[i]);

  unsigned short* ob = attn_out + ((size_t)b * SEQ + (size_t)qt * 64 + (wq << 4)) * DIM + h * HEAD_DIM;
#pragma unroll
  for (int d = 0; d < 4; ++d)
#pragma unroll
    for (int i = 0; i < 4; ++i)
      ob[(size_t)(quad * 4 + i) * DIM + d * 16 + lq] = f2bf(oacc[d][i] * rl4[i]);
}

extern "C" void kernel_launch(void* const* d_in, const int* in_sizes, int n_in,
                              void* d_out, int out_size, void* d_ws, size_t ws_size,
                              hipStream_t stream) {
  const float* x      = (const float*)d_in[0];
  const float* w_qkv  = (const float*)d_in[1];
  const float* w_proj = (const float*)d_in[2];
  const float* b_proj = (const float*)d_in[3];
  const float* curv   = (const float*)d_in[4];
  float* outp = (float*)d_out;

  float* ws = (float*)d_ws;
  // region A (bf16 3,145,728): v_tan_bf during QKV GEMM; attn_bf during proj GEMM
  unsigned short* v_tan_bf = (unsigned short*)ws;
  unsigned short* attn_bf  = (unsigned short*)ws;
  float* v_out = ws + 1572864;                         // 3,145,728 f
  unsigned short* qh  = (unsigned short*)(v_out + 3145728);
  unsigned short* kh  = qh + 3145728;
  unsigned short* vth = kh + 3145728;
  unsigned short* wqkv_bf  = vth + 3145728;            // 1,769,472 bf16
  unsigned short* wproj_bf = wqkv_bf + 1769472;        // 589,824 bf16
  float* qnA = (float*)(wproj_bf + 589824);            // 49,152 f each
  float* qnB = qnA + 49152;
  float* knA = qnB + 49152;
  float* knB = knA + 49152;

  log0_conv<<<dim3(ROWS / 4 + 2304), dim3(256), 0, stream>>>(
      x, curv, v_tan_bf, w_qkv, 1769472, w_proj, 589824, wqkv_bf, wproj_bf);
  gemm_qkv_fused<<<dim3(QKV_COLS / 128, ROWS / 128), dim3(256), 0, stream>>>(
      v_tan_bf, wqkv_bf, curv, qh, kh, vth, qnA, qnB, knA, knB);
  flash_mfma<<<dim3(768), dim3(512), 0, stream>>>(qh, kh, vth, qnA, qnB, knA, knB, attn_bf);
  gemm_nt_dbuf<64, 64><<<dim3(DIM / 64, ROWS / 64), dim3(256), 0, stream>>>(
      attn_bf, wproj_bf, v_out, ROWS, DIM, DIM, b_proj);
  exp0_out_kernel<<<dim3(ROWS / 4), dim3(256), 0, stream>>>(v_out, curv, outp);
}

// Round 5
// 198.033 us; speedup vs baseline: 1.6488x; 1.0211x over previous
//
#include <hip/hip_runtime.h>
#include <cmath>

#define ROWS 4096      // B*N
#define DIM 768        // D
#define QKV_COLS 2304  // 3*D
#define NHEAD 12
#define HEAD_DIM 64
#define SEQ 2048

static constexpr float EPS_F = 1e-8f;

typedef __bf16 bfrag __attribute__((ext_vector_type(8)));   // 8 bf16 = 4 VGPR (MFMA A/B frag)
typedef float  f32x4 __attribute__((ext_vector_type(4)));   // MFMA C/D frag
typedef float  f32x2 __attribute__((ext_vector_type(2)));   // packed v_pk_*_f32 pair

__device__ __forceinline__ float wave_sum64(float v) {
#pragma unroll
  for (int off = 1; off < 64; off <<= 1) v += __shfl_xor(v, off, 64);
  return v;
}

__device__ __forceinline__ unsigned short f2bf(float f) {
  unsigned u = __float_as_uint(f);
  u += 0x7fffu + ((u >> 16) & 1u);
  return (unsigned short)(u >> 16);
}

// fast tanh(x)/x for x>0:  t=(e-1)/(e+1), e=2^(x*2*log2e);  ->1 as x->0
__device__ __forceinline__ float tanh_over_x(float x) {
  const float e  = __builtin_amdgcn_exp2f(x * 2.8853900817779268f);
  const float th = (e - 1.0f) * __builtin_amdgcn_rcpf(e + 1.0f);
  return (x < 1e-4f) ? 1.0f : th * __builtin_amdgcn_rcpf(x);
}

__device__ __forceinline__ void gl_lds16(const void* g, void* l) {
  __builtin_amdgcn_global_load_lds((const __attribute__((address_space(1))) void*)g,
                                   (__attribute__((address_space(3))) void*)l, 16, 0, 0);
}

// ------------- fused: log0 -> bf16 tangent vectors  +  weight f32->bf16 casts -------------
__global__ __launch_bounds__(256) void log0_conv(const float* __restrict__ x,
                                                 const float* __restrict__ cptr,
                                                 unsigned short* __restrict__ vout,
                                                 const float* __restrict__ wa, int na,
                                                 const float* __restrict__ wb, int nb,
                                                 unsigned short* __restrict__ da,
                                                 unsigned short* __restrict__ db) {
  if (blockIdx.x >= ROWS / 4) {
    const int i = ((blockIdx.x - ROWS / 4) * 256 + threadIdx.x) * 4;
    const float* s;
    unsigned short* d;
    int j;
    if (i < na) { s = wa; d = da; j = i; }
    else { j = i - na; if (j >= nb) return; s = wb; d = db; }
    const float4 v = *(const float4*)(s + j);
    ushort4 o;
    o.x = f2bf(v.x); o.y = f2bf(v.y); o.z = f2bf(v.z); o.w = f2bf(v.w);
    *(ushort4*)(d + j) = o;
    return;
  }
  const int lane = threadIdx.x & 63;
  const int row  = (blockIdx.x << 2) + (threadIdx.x >> 6);
  const float* xr = x + (size_t)row * DIM;
  unsigned short* vr = vout + (size_t)row * DIM;
  float vals[12];
  float ss = 0.f;
#pragma unroll
  for (int i = 0; i < 12; ++i) {
    float t = xr[lane + (i << 6)];
    vals[i] = t;
    ss += t * t;
  }
  ss = wave_sum64(ss);
  const float sc  = sqrtf(cptr[0]);
  const float n   = fmaxf(sqrtf(ss), EPS_F);
  const float scn = sc * n;
  const float t   = fminf(scn, 1.0f - 1e-7f);
  const float ath = 0.34657359027997264f *
                    __builtin_amdgcn_logf((1.0f + t) * __builtin_amdgcn_rcpf(1.0f - t));
  const float f   = (scn < 1e-4f) ? 1.0f : ath * __builtin_amdgcn_rcpf(scn);
#pragma unroll
  for (int i = 0; i < 12; ++i) vr[lane + (i << 6)] = f2bf(vals[i] * f);
}

// ---------------- final exp0: out = tanh(sc*n) * v / (sc*n) ----------------
__global__ __launch_bounds__(256) void exp0_out_kernel(const float* __restrict__ vin,
                                                       const float* __restrict__ cptr,
                                                       float* __restrict__ outp) {
  const int lane = threadIdx.x & 63;
  const int row  = (blockIdx.x << 2) + (threadIdx.x >> 6);
  const float* vr = vin + (size_t)row * DIM;
  float* orow = outp + (size_t)row * DIM;
  float vals[12];
  float ss = 0.f;
#pragma unroll
  for (int i = 0; i < 12; ++i) {
    float t = vr[lane + (i << 6)];
    vals[i] = t;
    ss += t * t;
  }
  ss = wave_sum64(ss);
  const float sc = sqrtf(cptr[0]);
  const float n  = fmaxf(sqrtf(ss), EPS_F);
  const float f  = tanh_over_x(sc * n);
#pragma unroll
  for (int i = 0; i < 12; ++i) orow[lane + (i << 6)] = vals[i] * f;
}

// ---------------- MFMA GEMM NT, prefetch double-buffered (proj GEMM) ----------------
template<int BM, int BN>
__global__ __launch_bounds__(256) void gemm_nt_dbuf(const unsigned short* __restrict__ A,
                                                    const unsigned short* __restrict__ B,
                                                    float* __restrict__ C,
                                                    int M, int Ncols, int K,
                                                    const float* __restrict__ bias) {
  constexpr int FI = BM / 32;
  constexpr int FJ = BN / 32;
  constexpr int CH = BM / 64;
  __shared__ unsigned short As[2][BM * 32];
  __shared__ unsigned short Bs[2][BN * 32];
  const int tid = threadIdx.x;
  const int w = tid >> 6, lane = tid & 63;
  const int lq = lane & 15, quad = lane >> 4;
  const int wr = w >> 1, wc = w & 1;
  const int row0 = blockIdx.y * BM;
  const int col0 = blockIdx.x * BN;
  const int srow  = lane >> 2;
  const int skoff = (lane & 3) << 3;

  f32x4 acc[FI][FJ];
#pragma unroll
  for (int i = 0; i < FI; ++i)
#pragma unroll
    for (int j = 0; j < FJ; ++j) acc[i][j] = (f32x4){0.f, 0.f, 0.f, 0.f};

  auto pf = [&](int k0, int buf) {
#pragma unroll
    for (int c = 0; c < CH; ++c) {
      const int r = c * 64 + w * 16;
      gl_lds16(A + (size_t)(row0 + r + srow) * K + k0 + skoff, &As[buf][r * 32]);
      gl_lds16(B + (size_t)(col0 + r + srow) * K + k0 + skoff, &Bs[buf][r * 32]);
    }
  };

  pf(0, 0);
  const int NIT = K / 32;
  for (int it = 0; it < NIT; ++it) {
    const int buf = it & 1;
    __syncthreads();
    if (it + 1 < NIT) pf((it + 1) * 32, buf ^ 1);

    bfrag af[FI], bfg[FJ];
#pragma unroll
    for (int i = 0; i < FI; ++i)
      af[i] = *(const bfrag*)&As[buf][(wr * (BM / 2) + i * 16 + lq) * 32 + (quad << 3)];
#pragma unroll
    for (int j = 0; j < FJ; ++j)
      bfg[j] = *(const bfrag*)&Bs[buf][(wc * (BN / 2) + j * 16 + lq) * 32 + (quad << 3)];
#pragma unroll
    for (int i = 0; i < FI; ++i)
#pragma unroll
      for (int j = 0; j < FJ; ++j)
        acc[i][j] = __builtin_amdgcn_mfma_f32_16x16x32_bf16(af[i], bfg[j], acc[i][j], 0, 0, 0);
  }

#pragma unroll
  for (int i = 0; i < FI; ++i) {
    const int crow = row0 + wr * (BM / 2) + i * 16 + (quad << 2);
#pragma unroll
    for (int j = 0; j < FJ; ++j) {
      const int col = col0 + wc * (BN / 2) + j * 16 + lq;
      const float bj = bias ? bias[col] : 0.0f;
      float* cp = C + (size_t)crow * Ncols + col;
#pragma unroll
      for (int r = 0; r < 4; ++r)
        cp[(size_t)r * Ncols] = acc[i][j][r] + bj;
    }
  }
}

// ------------- fused QKV GEMM: 128x128 m97-style + exp0/norm/V-transpose epilogue -------
__global__ __launch_bounds__(256) void gemm_qkv_fused(const unsigned short* __restrict__ A,
                                                      const unsigned short* __restrict__ B,
                                                      const float* __restrict__ cptr,
                                                      unsigned short* __restrict__ qh,
                                                      unsigned short* __restrict__ kh,
                                                      unsigned short* __restrict__ vth,
                                                      float* __restrict__ qnA,
                                                      float* __restrict__ qnB,
                                                      float* __restrict__ knA,
                                                      float* __restrict__ knB) {
  __shared__ unsigned short As[2][128 * 32];
  __shared__ unsigned short Bs[2][128 * 32];
  const int tid = threadIdx.x;
  const int w = tid >> 6, lane = tid & 63;
  const int lq = lane & 15, quad = lane >> 4;
  const int wr = w >> 1, wc = w & 1;
  const int row0 = blockIdx.y << 7;
  const int col0 = blockIdx.x << 7;
  const int srow  = lane >> 2;
  const int skoff = (lane & 3) << 3;

  f32x4 acc[4][4];
#pragma unroll
  for (int i = 0; i < 4; ++i)
#pragma unroll
    for (int j = 0; j < 4; ++j) acc[i][j] = (f32x4){0.f, 0.f, 0.f, 0.f};

  auto pf = [&](int k0, int buf) {
#pragma unroll
    for (int c = 0; c < 2; ++c) {
      const int r = c * 64 + w * 16;
      gl_lds16(A + (size_t)(row0 + r + srow) * DIM + k0 + skoff, &As[buf][r * 32]);
      gl_lds16(B + (size_t)(col0 + r + srow) * DIM + k0 + skoff, &Bs[buf][r * 32]);
    }
  };

  pf(0, 0);
  for (int it = 0; it < DIM / 32; ++it) {
    const int buf = it & 1;
    __syncthreads();
    if (it + 1 < DIM / 32) pf((it + 1) * 32, buf ^ 1);

    bfrag af[4], bfg[4];
#pragma unroll
    for (int i = 0; i < 4; ++i)
      af[i] = *(const bfrag*)&As[buf][((wr << 6) + (i << 4) + lq) * 32 + (quad << 3)];
#pragma unroll
    for (int j = 0; j < 4; ++j)
      bfg[j] = *(const bfrag*)&Bs[buf][((wc << 6) + (j << 4) + lq) * 32 + (quad << 3)];
#pragma unroll
    for (int i = 0; i < 4; ++i)
#pragma unroll
      for (int j = 0; j < 4; ++j)
        acc[i][j] = __builtin_amdgcn_mfma_f32_16x16x32_bf16(af[i], bfg[j], acc[i][j], 0, 0, 0);
  }

  // ---- fused epilogue ----
  const int colw = col0 + (wc << 6);          // wave's 64-col base = one head slice
  const int seg  = colw / DIM;                // 0=q, 1=k, 2=v
  const int hh   = (colw % DIM) >> 6;
  const int rowb = row0 + (wr << 6);

  if (seg == 2) {
#pragma unroll
    for (int i = 0; i < 4; ++i)
#pragma unroll
      for (int r = 0; r < 4; ++r) {
        const int rowg = rowb + (i << 4) + (quad << 2) + r;
        const int bh = (rowg >> 11) * NHEAD + hh;
        const int n_ = rowg & 2047;
#pragma unroll
        for (int j = 0; j < 4; ++j)
          vth[((size_t)bh * HEAD_DIM + (j << 4) + lq) * SEQ + n_] = f2bf(acc[i][j][r]);
      }
  } else {
    unsigned short* dst = seg ? kh : qh;
    float* nA = seg ? knA : qnA;
    float* nB = seg ? knB : qnB;
    const float sc = sqrtf(cptr[0]);
#pragma unroll
    for (int i = 0; i < 4; ++i)
#pragma unroll
      for (int r = 0; r < 4; ++r) {
        float ss = acc[i][0][r] * acc[i][0][r];
        ss = fmaf(acc[i][1][r], acc[i][1][r], ss);
        ss = fmaf(acc[i][2][r], acc[i][2][r], ss);
        ss = fmaf(acc[i][3][r], acc[i][3][r], ss);
        ss += __shfl_xor(ss, 1, 64);
        ss += __shfl_xor(ss, 2, 64);
        ss += __shfl_xor(ss, 4, 64);
        ss += __shfl_xor(ss, 8, 64);
        const float nn = fmaxf(sqrtf(ss), EPS_F);
        const float f  = tanh_over_x(sc * nn);
        const int rowg = rowb + (i << 4) + (quad << 2) + r;
        const int bh = (rowg >> 11) * NHEAD + hh;
        const int n_ = rowg & 2047;
        unsigned short* rp = dst + ((size_t)bh * SEQ + n_) * HEAD_DIM;
#pragma unroll
        for (int j = 0; j < 4; ++j)
          rp[(j << 4) + lq] = f2bf(acc[i][j][r] * f);
        if (lq == 0) {
          const float nrm = ss * f * f;
          nA[(size_t)bh * SEQ + n_] = nrm;
          nB[(size_t)bh * SEQ + n_] = 1.0f / (1.0f - fminf(nrm, 0.99f));
        }
      }
  }
}

// ------------- MFMA flash attention, S^T form, in-block split-K (8 waves) -------------
// R1 structure (74.3us measured): 4 q-strips x 2 key-halves, 32-key double-buffered
// tiles, one barrier per tile (depth-1 prefetch is issued right after the barrier and
// drained a full iteration later -> latency covered). Ps stays an intra-wave LDS
// round-trip (1 b128 read; bpermute variant measured slower, R3). Transform written in
// f32x2 pairs so clang emits packed v_pk_*_f32 (halves the non-trans VALU slots).
__global__ __launch_bounds__(512, 6) void flash_mfma(const unsigned short* __restrict__ qh,
                                                     const unsigned short* __restrict__ kh,
                                                     const unsigned short* __restrict__ vth,
                                                     const float* __restrict__ qnA,
                                                     const float* __restrict__ qnB,
                                                     const float* __restrict__ knA,
                                                     const float* __restrict__ knB,
                                                     unsigned short* __restrict__ attn_out) {
  const int flat = blockIdx.x;
  const int bhid = flat % 24;
  const int qt   = flat / 24;
  const int h = bhid % NHEAD, b = bhid / NHEAD;
  const int bh = b * NHEAD + h;
  const int tid = threadIdx.x;
  const int w = tid >> 6, lane = tid & 63;
  const int lq = lane & 15, quad = lane >> 4;
  const int wq = w & 3;        // q-strip
  const int wh = w >> 2;       // key half

  __shared__ __align__(16) unsigned short Ks[2][2][32 * 64];  // [half][buf][key][hd] swizzled
  __shared__ __align__(16) unsigned short Vt[2][2][64 * 32];  // [half][buf] d-paired rows, swizzled
  __shared__ __align__(16) unsigned short Ps[8][16 * 32];     // per-wave [q][key] swizzled

  const unsigned short* qbase = qh + ((size_t)bh * SEQ + (size_t)qt * 64) * HEAD_DIM;
  const float* knAb = knA + (size_t)bh * SEQ;
  const float* knBb = knB + (size_t)bh * SEQ;
  const char* khb = (const char*)(kh + (size_t)bh * SEQ * HEAD_DIM);
  const char* vtb = (const char*)(vth + (size_t)bh * HEAD_DIM * SEQ);

  // K staging: this wave loads local rows wq*8..wq*8+7 of its half's 32-row tile
  const int krow = lane >> 3;                       // 0..7
  const int koff = ((wq << 3) + krow) * 128 + (((lane & 7) ^ krow) << 4);
  // V staging: chunk c of the 4KB d-paired tile; row2=d-pair, g = swizzled key-group
  const int c     = (wq << 6) + lane;               // 0..255
  const int vrow2 = c >> 3;
  const int vd    = (vrow2 << 1) + ((c >> 2) & 1);
  const int vg    = (c & 3) ^ (vrow2 & 3);
  const size_t voffb = (size_t)vd * (SEQ * 2);

  auto prefetch = [&](int kt, int buf) {
    const int kb = (wh << 10) + (kt << 5);
    gl_lds16(khb + (size_t)kb * 128 + koff, (char*)&Ks[wh][buf][0] + (wq << 10));
    gl_lds16(vtb + voffb + (size_t)(kb + (vg << 3)) * 2, (char*)&Vt[wh][buf][0] + (wq << 10));
  };

  // Q fragments (B operand in S^T)
  bfrag aq[2];
#pragma unroll
  for (int khf = 0; khf < 2; ++khf)
    aq[khf] = *(const bfrag*)(qbase + (size_t)((wq << 4) + lq) * HEAD_DIM + khf * 32 + quad * 8);

  const float qnS = qnA[(size_t)bh * SEQ + qt * 64 + (wq << 4) + lq];
  const float rqS = 2.0f * qnB[(size_t)bh * SEQ + qt * 64 + (wq << 4) + lq];

  bfrag ones;
#pragma unroll
  for (int j = 0; j < 8; ++j) ones[j] = (__bf16)1.0f;

  f32x4 oacc[4];
  f32x4 lacc = (f32x4){0.f, 0.f, 0.f, 0.f};
#pragma unroll
  for (int d = 0; d < 4; ++d) oacc[d] = (f32x4){0.f, 0.f, 0.f, 0.f};
  const int swz = lq & 7;             // Ks read swizzle (row&7)
  const int vsw = (lq >> 1) & 3;      // Vt read swizzle (row2&3)
  const int psx = ((lq >> 2) & 3) << 3;  // Ps swizzle (per q-row)

  prefetch(0, 0);
  for (int kt = 0; kt < 32; ++kt) {
    const int buf = kt & 1;
    const int key0 = (wh << 10) + (kt << 5);
    __syncthreads();  // tiles[buf] ready for both halves; all waves done with buf^1
    if (kt + 1 < 32) prefetch(kt + 1, buf ^ 1);

    // kn norms direct from global (L2-hot)
    f32x4 kna[2], knr[2];
#pragma unroll
    for (int st = 0; st < 2; ++st) {
      kna[st] = *(const f32x4*)(knAb + key0 + st * 16 + (quad << 2));
      knr[st] = *(const f32x4*)(knBb + key0 + st * 16 + (quad << 2));
    }

    // ---- S^T strip [32k x 16q] = K·Q^T via MFMA ----
    f32x4 s[2];
#pragma unroll
    for (int st = 0; st < 2; ++st) s[st] = (f32x4){0.f, 0.f, 0.f, 0.f};
#pragma unroll
    for (int khf = 0; khf < 2; ++khf)
#pragma unroll
      for (int st = 0; st < 2; ++st) {
        const bfrag ak = *(const bfrag*)&Ks[wh][buf][(st * 16 + lq) * 64 + (((khf << 2) + quad) ^ swz) * 8];
        s[st] = __builtin_amdgcn_mfma_f32_16x16x32_bf16(ak, aq[khf], s[st], 0, 0, 0);
      }

    // ---- w = (inner + sqrt(inner^2-1))^(-1/8); packed f32x2 pairs + v_perm pack ----
#pragma unroll
    for (int st = 0; st < 2; ++st) {
      const f32x2 qn2 = (f32x2){qnS, qnS};
      const f32x2 m2  = (f32x2){-2.f, -2.f};
      const f32x2 one2 = (f32x2){1.f, 1.f};
      const f32x2 neg2 = (f32x2){-1.f, -1.f};
      const f32x2 zr2 = (f32x2){0.f, 0.f};

      f32x2 s_lo = (f32x2){s[st][0], s[st][1]};
      f32x2 s_hi = (f32x2){s[st][2], s[st][3]};
      f32x2 ka_lo = (f32x2){kna[st][0], kna[st][1]};
      f32x2 ka_hi = (f32x2){kna[st][2], kna[st][3]};
      f32x2 kr_lo = (f32x2){knr[st][0], knr[st][1]};
      f32x2 kr_hi = (f32x2){knr[st][2], knr[st][3]};

      f32x2 tt_lo = __builtin_elementwise_fma(m2, s_lo, qn2 + ka_lo);
      f32x2 tt_hi = __builtin_elementwise_fma(m2, s_hi, qn2 + ka_hi);
      tt_lo = __builtin_elementwise_max(tt_lo, zr2);
      tt_hi = __builtin_elementwise_max(tt_hi, zr2);
      f32x2 rr_lo = kr_lo * rqS;
      f32x2 rr_hi = kr_hi * rqS;
      f32x2 in_lo = __builtin_elementwise_fma(tt_lo, rr_lo, one2);
      f32x2 in_hi = __builtin_elementwise_fma(tt_hi, rr_hi, one2);
      f32x2 r2_lo = __builtin_elementwise_fma(in_lo, in_lo, neg2);
      f32x2 r2_hi = __builtin_elementwise_fma(in_hi, in_hi, neg2);
      f32x2 rt_lo = (f32x2){__builtin_amdgcn_sqrtf(r2_lo.x), __builtin_amdgcn_sqrtf(r2_lo.y)};
      f32x2 rt_hi = (f32x2){__builtin_amdgcn_sqrtf(r2_hi.x), __builtin_amdgcn_sqrtf(r2_hi.y)};
      f32x2 y_lo = in_lo + rt_lo;
      f32x2 y_hi = in_hi + rt_hi;

      unsigned u[4];
      u[0] = __float_as_uint(__builtin_amdgcn_exp2f(-0.125f * __builtin_amdgcn_logf(y_lo.x)));
      u[1] = __float_as_uint(__builtin_amdgcn_exp2f(-0.125f * __builtin_amdgcn_logf(y_lo.y)));
      u[2] = __float_as_uint(__builtin_amdgcn_exp2f(-0.125f * __builtin_amdgcn_logf(y_hi.x)));
      u[3] = __float_as_uint(__builtin_amdgcn_exp2f(-0.125f * __builtin_amdgcn_logf(y_hi.y)));
      uint2 pk;
      pk.x = __builtin_amdgcn_perm(u[1], u[0], 0x07060302u);
      pk.y = __builtin_amdgcn_perm(u[3], u[2], 0x07060302u);
      *(uint2*)&Ps[w][(lq << 5) + (((st << 4) + (quad << 2)) ^ psx)] = pk;
    }

    // ---- O += P·V ; l += P·1 (intra-wave Ps, DS in-order: no barrier) ----
    const bfrag ap = *(const bfrag*)&Ps[w][(lq << 5) + ((quad << 3) ^ psx)];
    lacc = __builtin_amdgcn_mfma_f32_16x16x32_bf16(ap, ones, lacc, 0, 0, 0);
#pragma unroll
    for (int d = 0; d < 4; ++d) {
      const int dd = (d << 4) + lq;
      const bfrag bv = *(const bfrag*)&Vt[wh][buf][(dd >> 1) * 64 + (dd & 1) * 32 + (quad ^ vsw) * 8];
      oacc[d] = __builtin_amdgcn_mfma_f32_16x16x32_bf16(ap, bv, oacc[d], 0, 0, 0);
    }
  }

  // ---- combine halves through LDS (reuse tile space) ----
  __syncthreads();  // all waves done reading Ks/Vt
  float* cb = (float*)&Ks[0][0][0];   // 16 KiB: oacc of upper half
  float* lb = (float*)&Vt[0][0][0];   // lacc of upper half
  const int ci = (wq << 6) + lane;
  if (wh) {
    float* p = cb + ci * 16;
#pragma unroll
    for (int d = 0; d < 4; ++d) *(f32x4*)(p + (d << 2)) = oacc[d];
    *(f32x4*)(lb + (ci << 2)) = lacc;
  }
  __syncthreads();
  if (wh) return;

  {
    const float* p = cb + ci * 16;
#pragma unroll
    for (int d = 0; d < 4; ++d) oacc[d] += *(const f32x4*)(p + (d << 2));
    lacc += *(const f32x4*)(lb + (ci << 2));
  }

  float rl4[4];
#pragma unroll
  for (int i = 0; i < 4; ++i) rl4[i] = __builtin_amdgcn_rcpf(lacc[i]);

  unsigned short* ob = attn_out + ((size_t)b * SEQ + (size_t)qt * 64 + (wq << 4)) * DIM + h * HEAD_DIM;
#pragma unroll
  for (int d = 0; d < 4; ++d)
#pragma unroll
    for (int i = 0; i < 4; ++i)
      ob[(size_t)(quad * 4 + i) * DIM + d * 16 + lq] = f2bf(oacc[d][i] * rl4[i]);
}

extern "C" void kernel_launch(void* const* d_in, const int* in_sizes, int n_in,
                              void* d_out, int out_size, void* d_ws, size_t ws_size,
                              hipStream_t stream) {
  const float* x      = (const float*)d_in[0];
  const float* w_qkv  = (const float*)d_in[1];
  const float* w_proj = (const float*)d_in[2];
  const float* b_proj = (const float*)d_in[3];
  const float* curv   = (const float*)d_in[4];
  float* outp = (float*)d_out;

  float* ws = (float*)d_ws;
  // region A (bf16 3,145,728): v_tan_bf during QKV GEMM; attn_bf during proj GEMM
  unsigned short* v_tan_bf = (unsigned short*)ws;
  unsigned short* attn_bf  = (unsigned short*)ws;
  float* v_out = ws + 1572864;                         // 3,145,728 f
  unsigned short* qh  = (unsigned short*)(v_out + 3145728);
  unsigned short* kh  = qh + 3145728;
  unsigned short* vth = kh + 3145728;
  unsigned short* wqkv_bf  = vth + 3145728;            // 1,769,472 bf16
  unsigned short* wproj_bf = wqkv_bf + 1769472;        // 589,824 bf16
  float* qnA = (float*)(wproj_bf + 589824);            // 49,152 f each
  float* qnB = qnA + 49152;
  float* knA = qnB + 49152;
  float* knB = knA + 49152;

  log0_conv<<<dim3(ROWS / 4 + 2304), dim3(256), 0, stream>>>(
      x, curv, v_tan_bf, w_qkv, 1769472, w_proj, 589824, wqkv_bf, wproj_bf);
  gemm_qkv_fused<<<dim3(QKV_COLS / 128, ROWS / 128), dim3(256), 0, stream>>>(
      v_tan_bf, wqkv_bf, curv, qh, kh, vth, qnA, qnB, knA, knB);
  flash_mfma<<<dim3(768), dim3(512), 0, stream>>>(qh, kh, vth, qnA, qnB, knA, knB, attn_bf);
  gemm_nt_dbuf<64, 64><<<dim3(DIM / 64, ROWS / 64), dim3(256), 0, stream>>>(
      attn_bf, wproj_bf, v_out, ROWS, DIM, DIM, b_proj);
  exp0_out_kernel<<<dim3(ROWS / 4), dim3(256), 0, stream>>>(v_out, curv, outp);
}